// Round 12
// baseline (2640.496 us; speedup 1.0000x reference)
//
#include <hip/hip_runtime.h>

typedef int   v4i  __attribute__((ext_vector_type(4)));
typedef short bf8  __attribute__((ext_vector_type(8)));   // 8 bf16 (4 VGPRs)
typedef float f32x4 __attribute__((ext_vector_type(4)));

#define B_   64
#define HIDDEN_ 4096
#define NH_  32
#define NKV_ 8
#define HD_  128
#define S_   2048
#define NQKV 6144            // (NH + 2*NKV)*HD
#define CHUNK 256            // attention flash-decoding chunk (16 pages)
#define NCHUNK 8
#define KSPLIT 8
#define QKV_PART (64 * NQKV) // ints per k-partial

// DIAGNOSTIC ROUND: rep-wrapped kernels (idempotent) to surface each in
// rocprof top-5 with clean counters.  Structure is R9 verbatim otherwise.
#define QKV_REP   48
#define ATTN_REP  3
#define OPROJ_REP 48

// Harness uploads ALL integer inputs widened to int32; low byte is the i8 payload.
__device__ __forceinline__ unsigned pack_i8(int a, int b, int c, int d) {
    return (a & 0xff) | ((b & 0xff) << 8) | ((c & 0xff) << 16) | (d << 24);
}

// ---------------------------------------------------------------------------
// Kernel 1: int8 QKV GEMM, K-split x8.  grid (96, 8) = 768 blocks.
__global__ __launch_bounds__(256) void qkv_gemm(const int* __restrict__ A,
                                                const int* __restrict__ W,
                                                int* __restrict__ Cp) {
    __shared__ signed char Wl[2][64 * 80];
    const int tid = threadIdx.x;
    const int n0  = blockIdx.x * 64;
    const int ky  = blockIdx.y;
    const int kbeg = ky * (HIDDEN_ / KSPLIT);     // 512
    const int wv  = tid >> 6;
    const int l   = tid & 63;
    const int lr  = l & 15;
    const int lk  = l >> 4;
    const int sn  = tid & 63;
    const int sk  = (tid >> 6) * 16;

    const int* Wg = W + (long)(kbeg + sk) * NQKV + n0 + sn;

#define LOADW(R, CH) { const int* wp = Wg + (long)(CH) * 64 * NQKV;              \
    _Pragma("unroll") for (int j = 0; j < 16; ++j) R[j] = wp[j * NQKV]; }
#define STAGEW(R, BUF) { unsigned d0 = pack_i8(R[0],R[1],R[2],R[3]);             \
    unsigned d1 = pack_i8(R[4],R[5],R[6],R[7]);                                  \
    unsigned d2 = pack_i8(R[8],R[9],R[10],R[11]);                                \
    unsigned d3 = pack_i8(R[12],R[13],R[14],R[15]);                              \
    v4i t = {(int)d0,(int)d1,(int)d2,(int)d3};                                   \
    *(v4i*)&Wl[BUF][sn * 80 + sk] = t; }
#define COMPW(BUF, CH) { const int* ap = A + (long)(wv*16+lr)*HIDDEN_ + kbeg + (CH)*64 + lk*16; \
    unsigned av[4];                                                              \
    _Pragma("unroll") for (int j = 0; j < 4; ++j) {                              \
        int4 t = *(const int4*)(ap + 4*j); av[j] = pack_i8(t.x,t.y,t.z,t.w); }   \
    v4i a = *(v4i*)av;                                                           \
    _Pragma("unroll") for (int nt = 0; nt < 4; ++nt) {                           \
        v4i bb = *(const v4i*)&Wl[BUF][(nt*16+lr)*80 + lk*16];                   \
        acc[nt] = __builtin_amdgcn_mfma_i32_16x16x64_i8(a, bb, acc[nt], 0,0,0); } }

#pragma unroll 1
    for (int rep = 0; rep < QKV_REP; ++rep) {
        v4i acc[4] = {v4i{0,0,0,0}, v4i{0,0,0,0}, v4i{0,0,0,0}, v4i{0,0,0,0}};
        int rA[16], rB[16];
        LOADW(rA, 0);
#pragma unroll 1
        for (int ch = 0; ch < 8; ch += 2) {
            STAGEW(rA, 0);
            LOADW(rB, ch + 1);
            __syncthreads();
            COMPW(0, ch);
            STAGEW(rB, 1);
            if (ch < 6) LOADW(rA, ch + 2);
            __syncthreads();
            COMPW(1, ch + 1);
        }
        int* Co = Cp + (long)ky * QKV_PART;
#pragma unroll
        for (int nt = 0; nt < 4; ++nt)
#pragma unroll
            for (int r = 0; r < 4; ++r) {
                int m = wv * 16 + (l >> 4) * 4 + r;
                int n = n0 + nt * 16 + (l & 15);
                Co[m * NQKV + n] = acc[nt][r];
            }
        __syncthreads();   // rep boundary
    }
#undef LOADW
#undef STAGEW
#undef COMPW
}

// ---------------------------------------------------------------------------
// Kernel 2: 8-partial reduce + dequant + neox RoPE.  grid (64, 4).  (R9 verbatim)
__device__ __forceinline__ float rd8(const int* __restrict__ q, int idx) {
    int v = 0;
#pragma unroll
    for (int p = 0; p < KSPLIT; ++p) v += q[p * QKV_PART + idx];
    return (float)v;
}

__global__ __launch_bounds__(256) void rope_dequant(const int* __restrict__ qkvp,
                                                    const int* __restrict__ positions,
                                                    const float* qs_p, const float* ks_p,
                                                    const float* vs_p,
                                                    float* __restrict__ qf,
                                                    float* __restrict__ knew,
                                                    float* __restrict__ vnew) {
    const int b = blockIdx.x, part = blockIdx.y;
    const int tid = threadIdx.x;
    __shared__ float cs[64], sn[64];
    const float qs = qs_p[0], ks = ks_p[0], vs = vs_p[0];
    if (tid < 64) {
        float invf = 1.0f / powf(10000.0f, (float)tid * (1.0f / 64.0f));
        float ang  = (float)positions[b] * invf;
        cs[tid] = cosf(ang);
        sn[tid] = sinf(ang);
    }
    __syncthreads();
    const int base = b * NQKV;
    if (part < 2) {
        for (int t = tid; t < 1024; t += 256) {
            int head = part * 16 + (t >> 6), i = t & 63;
            float x1 = rd8(qkvp, base + head * 128 + i) * qs;
            float x2 = rd8(qkvp, base + head * 128 + 64 + i) * qs;
            float c = cs[i], s = sn[i];
            qf[(b * NH_ + head) * 128 + i]      = x1 * c - x2 * s;
            qf[(b * NH_ + head) * 128 + 64 + i] = x2 * c + x1 * s;
        }
    } else if (part == 2) {
        for (int t = tid; t < 512; t += 256) {
            int h = t >> 6, i = t & 63;
            float x1 = rd8(qkvp, base + 4096 + h * 128 + i) * ks;
            float x2 = rd8(qkvp, base + 4096 + h * 128 + 64 + i) * ks;
            float c = cs[i], s = sn[i];
            knew[(b * NKV_ + h) * 128 + i]      = x1 * c - x2 * s;
            knew[(b * NKV_ + h) * 128 + 64 + i] = x2 * c + x1 * s;
        }
    } else {
        for (int t = tid; t < 1024; t += 256) {
            int h = t >> 7, d = t & 127;
            vnew[(b * NKV_ + h) * 128 + d] = rd8(qkvp, base + 5120 + h * 128 + d) * vs;
        }
    }
}

// ---------------------------------------------------------------------------
// Kernel 3: flash-decoding attention chunk.  grid (NCHUNK, B*NKV).
// R9 structure, rep-wrapped x3 for counters.
__global__ __launch_bounds__(256) void attn_decode(const int* __restrict__ kc,
                                                   const int* __restrict__ vc,
                                                   const int* __restrict__ btab,
                                                   const int* __restrict__ ctx_lens,
                                                   const float* __restrict__ qf,
                                                   const float* ks_p, const float* vs_p,
                                                   float* __restrict__ po,
                                                   float* __restrict__ pm,
                                                   float* __restrict__ pl) {
    const int c  = blockIdx.x;
    const int bh = blockIdx.y;
    const int b = bh >> 3, h = bh & 7;
    const int ctx = ctx_lens[b];
    const int s0g = c * CHUNK;
    const int n = min(ctx - s0g, CHUNK);
    if (n <= 0) return;

    __shared__ float sc[4][264];        // CHUNK + pad
    __shared__ float opart[512][9];     // [g*128+d][spart]
    __shared__ int   bts[CHUNK / 16];

    const int tid = threadIdx.x;
    const int wv  = tid >> 6;
    const int l   = tid & 63;
    const int tok = l >> 4;             // token within 4-group
    const int dq  = l & 15;             // 8-dim slice

    const float kss = ks_p[0] * 0.08838834764831845f;
    const float vscale = vs_p[0];

#pragma unroll 1
    for (int rep = 0; rep < ATTN_REP; ++rep) {
        if (tid < CHUNK / 16) bts[tid] = btab[b * 128 + (s0g >> 4) + tid];

        float qr[4][8];
#pragma unroll
        for (int g = 0; g < 4; ++g) {
            const float* qp = qf + (long)(b * NH_ + h * 4 + g) * 128 + dq * 8;
            float4 v0 = *(const float4*)(qp);
            float4 v1 = *(const float4*)(qp + 4);
            qr[g][0]=v0.x; qr[g][1]=v0.y; qr[g][2]=v0.z; qr[g][3]=v0.w;
            qr[g][4]=v1.x; qr[g][5]=v1.y; qr[g][6]=v1.z; qr[g][7]=v1.w;
        }
        __syncthreads();   // bts ready

        // ---- pass 1: scores.
        {
            const int nsweep = (n + 15) >> 4;
            int srel = wv * 4 + tok;
            int4 w0, w1;
            {
                int seff = min(srel, n - 1);
                int blk = bts[seff >> 4];
                const int* kp = kc + (long)(blk * 16 + (seff & 15)) * 1024 + h * 128 + dq * 8;
                w0 = *(const int4*)kp;
                w1 = *(const int4*)(kp + 4);
            }
#pragma unroll 1
            for (int it = 0; it < nsweep; ++it) {
                int4 u0, u1;
                const bool more = (it + 1 < nsweep);
                if (more) {
                    int snx = min(srel + 16, n - 1);
                    int blk = bts[snx >> 4];
                    const int* kp = kc + (long)(blk * 16 + (snx & 15)) * 1024 + h * 128 + dq * 8;
                    u0 = *(const int4*)kp;
                    u1 = *(const int4*)(kp + 4);
                }
                float kf[8];
                kf[0]=(float)w0.x; kf[1]=(float)w0.y; kf[2]=(float)w0.z; kf[3]=(float)w0.w;
                kf[4]=(float)w1.x; kf[5]=(float)w1.y; kf[6]=(float)w1.z; kf[7]=(float)w1.w;
                float p0 = 0.f, p1 = 0.f, p2 = 0.f, p3 = 0.f;
#pragma unroll
                for (int j = 0; j < 8; ++j) {
                    p0 += qr[0][j] * kf[j];
                    p1 += qr[1][j] * kf[j];
                    p2 += qr[2][j] * kf[j];
                    p3 += qr[3][j] * kf[j];
                }
#pragma unroll
                for (int off = 1; off < 16; off <<= 1) {
                    p0 += __shfl_xor(p0, off, 16);
                    p1 += __shfl_xor(p1, off, 16);
                    p2 += __shfl_xor(p2, off, 16);
                    p3 += __shfl_xor(p3, off, 16);
                }
                if (srel < n && dq < 4) {
                    float psel = (dq == 0) ? p0 : (dq == 1) ? p1 : (dq == 2) ? p2 : p3;
                    sc[dq][srel] = psel * kss;
                }
                if (more) { w0 = u0; w1 = u1; }
                srel += 16;
            }
        }
        __syncthreads();

        // ---- softmax per head.
        {
            float m = -1e30f;
            for (int s = l; s < n; s += 64) m = fmaxf(m, sc[wv][s]);
#pragma unroll
            for (int off = 1; off < 64; off <<= 1) m = fmaxf(m, __shfl_xor(m, off, 64));
            float sum = 0.f;
            for (int s = l; s < n; s += 64) {
                float e = __expf(sc[wv][s] - m);
                sc[wv][s] = e;
                sum += e;
            }
#pragma unroll
            for (int off = 1; off < 64; off <<= 1) sum += __shfl_xor(sum, off, 64);
            if (l == 0) {
                int idx = (c * 512 + bh) * 4 + wv;
                pm[idx] = m;
                pl[idx] = sum;
            }
        }
        __syncthreads();

        // ---- pass 2: PV.
        const int d4 = tid & 31;
        const int sp = tid >> 5;
        float acc[4][4] = {};
        int s = sp;
#pragma unroll 1
        for (; s + 56 < n; s += 64) {
            int4 w[8];
#pragma unroll
            for (int j = 0; j < 8; ++j) {
                int ss = s + 8 * j;
                int blk = bts[ss >> 4];
                w[j] = *(const int4*)(vc + (long)(blk * 16 + (ss & 15)) * 1024 + h * 128 + d4 * 4);
            }
#pragma unroll
            for (int j = 0; j < 8; ++j) {
                int ss = s + 8 * j;
                float v0 = (float)w[j].x, v1 = (float)w[j].y, v2 = (float)w[j].z, v3 = (float)w[j].w;
#pragma unroll
                for (int g = 0; g < 4; ++g) {
                    float p = sc[g][ss];
                    acc[g][0] += p * v0; acc[g][1] += p * v1;
                    acc[g][2] += p * v2; acc[g][3] += p * v3;
                }
            }
        }
#pragma unroll 1
        for (; s < n; s += 8) {
            int blk = bts[s >> 4];
            int4 w = *(const int4*)(vc + (long)(blk * 16 + (s & 15)) * 1024 + h * 128 + d4 * 4);
            float v0 = (float)w.x, v1 = (float)w.y, v2 = (float)w.z, v3 = (float)w.w;
#pragma unroll
            for (int g = 0; g < 4; ++g) {
                float p = sc[g][s];
                acc[g][0] += p * v0; acc[g][1] += p * v1;
                acc[g][2] += p * v2; acc[g][3] += p * v3;
            }
        }
#pragma unroll
        for (int g = 0; g < 4; ++g)
#pragma unroll
            for (int j = 0; j < 4; ++j)
                opart[g * 128 + d4 * 4 + j][sp] = acc[g][j];
        __syncthreads();

        for (int oi = tid; oi < 512; oi += 256) {
            float o = 0.f;
#pragma unroll
            for (int p = 0; p < 8; ++p) o += opart[oi][p];
            po[(long)((c * 512 + bh) * 4 + (oi >> 7)) * 128 + (oi & 127)] = o * vscale;
        }
        __syncthreads();   // rep boundary
    }
}

// ---------------------------------------------------------------------------
// Kernel 4: merge chunk partials + new-token term -> attn (bf16).  (R9 verbatim)
__global__ __launch_bounds__(256) void attn_merge(const float* __restrict__ qf,
                                                  const float* __restrict__ knew,
                                                  const float* __restrict__ vnew,
                                                  const int* __restrict__ ctx_lens,
                                                  const float* __restrict__ po,
                                                  const float* __restrict__ pm,
                                                  const float* __restrict__ pl,
                                                  unsigned short* __restrict__ attn) {
    const int bh = blockIdx.x;
    const int b = bh >> 3, h = bh & 7;
    const int ctx = ctx_lens[b];
    const int nc = (ctx + CHUNK - 1) / CHUNK;
    const int tid = threadIdx.x;
    const int wv = tid >> 6, l = tid & 63;
    __shared__ float snew_s[4];

    {
        const float* kn = knew + (b * NKV_ + h) * 128;
        const float* qp = qf + (long)(b * NH_ + h * 4 + wv) * 128;
        float p = qp[l] * kn[l] + qp[l + 64] * kn[l + 64];
#pragma unroll
        for (int off = 1; off < 64; off <<= 1) p += __shfl_xor(p, off, 64);
        if (l == 0) snew_s[wv] = p * 0.08838834764831845f;
    }
    __syncthreads();

    for (int oi = tid; oi < 512; oi += 256) {
        int g = oi >> 7, d = oi & 127;
        float snew = snew_s[g];
        float M = snew;
        for (int c = 0; c < nc; ++c)
            M = fmaxf(M, pm[(c * 512 + bh) * 4 + g]);
        float wn = __expf(snew - M);
        float L = wn;
        float O = wn * vnew[(b * NKV_ + h) * 128 + d];
        for (int c = 0; c < nc; ++c) {
            float w = __expf(pm[(c * 512 + bh) * 4 + g] - M);
            L += pl[(c * 512 + bh) * 4 + g] * w;
            O += po[(long)((c * 512 + bh) * 4 + g) * 128 + d] * w;
        }
        float res = O / L;
        unsigned int u = __float_as_uint(res);
        unsigned int r = (u + 0x7fffu + ((u >> 16) & 1u)) >> 16;   // RNE to bf16
        attn[b * 4096 + (h * 4 + g) * 128 + d] = (unsigned short)r;
    }
}

// ---------------------------------------------------------------------------
// Kernel 5: o_proj bf16 MFMA.  grid 256, rep-wrapped x48 for counters.
__global__ __launch_bounds__(256) void oproj(const unsigned short* __restrict__ Abf,
                                             const int* __restrict__ W,
                                             const float* os_p,
                                             float* __restrict__ out) {
    __shared__ unsigned short Wl[4][16 * 72];
    const int tid = threadIdx.x;
    const int n0  = blockIdx.x * 16;
    const int wv  = tid >> 6, l = tid & 63;
    const int lr  = l & 15, lk = l >> 4;
    const float osc = os_p[0];
    const int sn  = tid & 15;
    const int sk4 = (tid >> 4) * 4;

    const int* Wg = W + (long)sk4 * HIDDEN_ + n0 + sn;

#define LOADO(R, CH) { const int* wp = Wg + (long)(CH) * 64 * HIDDEN_;           \
    _Pragma("unroll") for (int j = 0; j < 4; ++j) R[j] = wp[j * HIDDEN_]; }
#define STAGEO(R, BUF) { ushort4 hb;                                             \
    hb.x = (unsigned short)(__float_as_uint((float)R[0]) >> 16);                 \
    hb.y = (unsigned short)(__float_as_uint((float)R[1]) >> 16);                 \
    hb.z = (unsigned short)(__float_as_uint((float)R[2]) >> 16);                 \
    hb.w = (unsigned short)(__float_as_uint((float)R[3]) >> 16);                 \
    *(ushort4*)&Wl[BUF][sn * 72 + sk4] = hb; }
#define COMPO(BUF, CH) { _Pragma("unroll") for (int kh = 0; kh < 2; ++kh) {      \
    bf8 a = *(const bf8*)(Abf + (long)(wv*16+lr)*HIDDEN_ + (CH)*64 + kh*32 + lk*8); \
    bf8 bb = *(const bf8*)&Wl[BUF][lr * 72 + kh * 32 + lk * 8];                  \
    acc = __builtin_amdgcn_mfma_f32_16x16x32_bf16(a, bb, acc, 0, 0, 0); } }

#pragma unroll 1
    for (int rep = 0; rep < OPROJ_REP; ++rep) {
        f32x4 acc = f32x4{0.f, 0.f, 0.f, 0.f};
        int r0[4], r1[4], r2[4], r3[4];
        LOADO(r0, 0); LOADO(r1, 1); LOADO(r2, 2); LOADO(r3, 3);
#pragma unroll 1
        for (int ch = 0; ch < 64; ch += 4) {
            STAGEO(r0, 0); STAGEO(r1, 1); STAGEO(r2, 2); STAGEO(r3, 3);
            __syncthreads();
            if (ch < 60) { LOADO(r0, ch+4); LOADO(r1, ch+5); LOADO(r2, ch+6); LOADO(r3, ch+7); }
            COMPO(0, ch); COMPO(1, ch+1); COMPO(2, ch+2); COMPO(3, ch+3);
            __syncthreads();
        }
#pragma unroll
        for (int r = 0; r < 4; ++r) {
            int m = wv * 16 + (l >> 4) * 4 + r;
            int n = n0 + (l & 15);
            out[m * HIDDEN_ + n] = acc[r] * osc;
        }
        __syncthreads();   // rep boundary
    }
#undef LOADO
#undef STAGEO
#undef COMPO
}

// ---------------------------------------------------------------------------
extern "C" void kernel_launch(void* const* d_in, const int* in_sizes, int n_in,
                              void* d_out, int out_size, void* d_ws, size_t ws_size,
                              hipStream_t stream) {
    const int*   positions = (const int*)d_in[0];
    const int*   hidden    = (const int*)d_in[1];
    const int*   w_qkv     = (const int*)d_in[2];
    const int*   w_o       = (const int*)d_in[3];
    const int*   kcache    = (const int*)d_in[4];
    const int*   vcache    = (const int*)d_in[5];
    const int*   btab      = (const int*)d_in[6];
    const int*   ctxl      = (const int*)d_in[7];
    const float* qs        = (const float*)d_in[8];
    const float* ks        = (const float*)d_in[9];
    const float* vs        = (const float*)d_in[10];
    const float* os        = (const float*)d_in[11];

    // po (8.4 MB) aliases qkvp (12.6 MB): qkvp dead after rope_dequant.
    char* ws = (char*)d_ws;
    int*            qkvp  = (int*)ws;                           // 12,582,912
    float*          po    = (float*)ws;                         //  8,388,608 (alias)
    float*          qf    = (float*)(ws + 16777216);            //  1,048,576
    float*          knew  = (float*)(ws + 17825792);            //    262,144
    float*          vnew  = (float*)(ws + 18087936);            //    262,144
    unsigned short* attnb = (unsigned short*)(ws + 18350080);   //    524,288
    float*          pm    = (float*)(ws + 18874368);            //     65,536
    float*          pl    = (float*)(ws + 19005440);            //     65,536

    qkv_gemm<<<dim3(NQKV / 64, KSPLIT), 256, 0, stream>>>(hidden, w_qkv, qkvp);
    rope_dequant<<<dim3(B_, 4), 256, 0, stream>>>(qkvp, positions, qs, ks, vs, qf, knew, vnew);
    attn_decode<<<dim3(NCHUNK, B_ * NKV_), 256, 0, stream>>>(kcache, vcache, btab, ctxl,
                                                             qf, ks, vs, po, pm, pl);
    attn_merge<<<B_ * NKV_, 256, 0, stream>>>(qf, knew, vnew, ctxl, po, pm, pl, attnb);
    oproj<<<HIDDEN_ / 16, 256, 0, stream>>>(attnb, w_o, os, (float*)d_out);
}

// Round 13
// 215.257 us; speedup vs baseline: 12.2667x; 12.2667x over previous
//
#include <hip/hip_runtime.h>

typedef int   v4i  __attribute__((ext_vector_type(4)));
typedef short bf8  __attribute__((ext_vector_type(8)));   // 8 bf16 (4 VGPRs)
typedef float f32x4 __attribute__((ext_vector_type(4)));

#define B_   64
#define HIDDEN_ 4096
#define NH_  32
#define NKV_ 8
#define HD_  128
#define S_   2048
#define NQKV 6144            // (NH + 2*NKV)*HD
#define CHUNK 256            // attention flash-decoding chunk (16 pages)
#define NCHUNK 8
#define KSPLIT 8
#define OSPLIT 16            // oproj K-split
#define QKV_PART (64 * NQKV) // ints per k-partial
#define OPROJ_PART (64 * HIDDEN_)

// Harness uploads ALL integer inputs widened to int32; low byte is the i8 payload.
__device__ __forceinline__ unsigned pack_i8(int a, int b, int c, int d) {
    return (a & 0xff) | ((b & 0xff) << 8) | ((c & 0xff) << 16) | (d << 24);
}

// ---------------------------------------------------------------------------
// Kernel 1: int8 QKV GEMM, K-split x8.  grid (96, 8) = 768 blocks.  (R9 verbatim;
// measured ~15 us = ~6.7 TB/s on w_qkv -> at roofline, do not touch)
__global__ __launch_bounds__(256) void qkv_gemm(const int* __restrict__ A,
                                                const int* __restrict__ W,
                                                int* __restrict__ Cp) {
    __shared__ signed char Wl[2][64 * 80];
    const int tid = threadIdx.x;
    const int n0  = blockIdx.x * 64;
    const int ky  = blockIdx.y;
    const int kbeg = ky * (HIDDEN_ / KSPLIT);     // 512
    const int wv  = tid >> 6;
    const int l   = tid & 63;
    const int lr  = l & 15;
    const int lk  = l >> 4;
    const int sn  = tid & 63;
    const int sk  = (tid >> 6) * 16;

    const int* Wg = W + (long)(kbeg + sk) * NQKV + n0 + sn;

    v4i acc[4] = {v4i{0,0,0,0}, v4i{0,0,0,0}, v4i{0,0,0,0}, v4i{0,0,0,0}};
    int rA[16], rB[16];

#define LOADW(R, CH) { const int* wp = Wg + (long)(CH) * 64 * NQKV;              \
    _Pragma("unroll") for (int j = 0; j < 16; ++j) R[j] = wp[j * NQKV]; }
#define STAGEW(R, BUF) { unsigned d0 = pack_i8(R[0],R[1],R[2],R[3]);             \
    unsigned d1 = pack_i8(R[4],R[5],R[6],R[7]);                                  \
    unsigned d2 = pack_i8(R[8],R[9],R[10],R[11]);                                \
    unsigned d3 = pack_i8(R[12],R[13],R[14],R[15]);                              \
    v4i t = {(int)d0,(int)d1,(int)d2,(int)d3};                                   \
    *(v4i*)&Wl[BUF][sn * 80 + sk] = t; }
#define COMPW(BUF, CH) { const int* ap = A + (long)(wv*16+lr)*HIDDEN_ + kbeg + (CH)*64 + lk*16; \
    unsigned av[4];                                                              \
    _Pragma("unroll") for (int j = 0; j < 4; ++j) {                              \
        int4 t = *(const int4*)(ap + 4*j); av[j] = pack_i8(t.x,t.y,t.z,t.w); }   \
    v4i a = *(v4i*)av;                                                           \
    _Pragma("unroll") for (int nt = 0; nt < 4; ++nt) {                           \
        v4i bb = *(const v4i*)&Wl[BUF][(nt*16+lr)*80 + lk*16];                   \
        acc[nt] = __builtin_amdgcn_mfma_i32_16x16x64_i8(a, bb, acc[nt], 0,0,0); } }

    LOADW(rA, 0);
#pragma unroll 1
    for (int ch = 0; ch < 8; ch += 2) {
        STAGEW(rA, 0);
        LOADW(rB, ch + 1);
        __syncthreads();
        COMPW(0, ch);
        STAGEW(rB, 1);
        if (ch < 6) LOADW(rA, ch + 2);
        __syncthreads();
        COMPW(1, ch + 1);
    }
    int* Co = Cp + (long)ky * QKV_PART;
#pragma unroll
    for (int nt = 0; nt < 4; ++nt)
#pragma unroll
        for (int r = 0; r < 4; ++r) {
            int m = wv * 16 + (l >> 4) * 4 + r;
            int n = n0 + nt * 16 + (l & 15);
            Co[m * NQKV + n] = acc[nt][r];
        }
#undef LOADW
#undef STAGEW
#undef COMPW
}

// ---------------------------------------------------------------------------
// Kernel 2: 8-partial reduce + dequant + neox RoPE.  grid (64, 4).  (R9 verbatim)
__device__ __forceinline__ float rd8(const int* __restrict__ q, int idx) {
    int v = 0;
#pragma unroll
    for (int p = 0; p < KSPLIT; ++p) v += q[p * QKV_PART + idx];
    return (float)v;
}

__global__ __launch_bounds__(256) void rope_dequant(const int* __restrict__ qkvp,
                                                    const int* __restrict__ positions,
                                                    const float* qs_p, const float* ks_p,
                                                    const float* vs_p,
                                                    float* __restrict__ qf,
                                                    float* __restrict__ knew,
                                                    float* __restrict__ vnew) {
    const int b = blockIdx.x, part = blockIdx.y;
    const int tid = threadIdx.x;
    __shared__ float cs[64], sn[64];
    const float qs = qs_p[0], ks = ks_p[0], vs = vs_p[0];
    if (tid < 64) {
        float invf = 1.0f / powf(10000.0f, (float)tid * (1.0f / 64.0f));
        float ang  = (float)positions[b] * invf;
        cs[tid] = cosf(ang);
        sn[tid] = sinf(ang);
    }
    __syncthreads();
    const int base = b * NQKV;
    if (part < 2) {
        for (int t = tid; t < 1024; t += 256) {
            int head = part * 16 + (t >> 6), i = t & 63;
            float x1 = rd8(qkvp, base + head * 128 + i) * qs;
            float x2 = rd8(qkvp, base + head * 128 + 64 + i) * qs;
            float c = cs[i], s = sn[i];
            qf[(b * NH_ + head) * 128 + i]      = x1 * c - x2 * s;
            qf[(b * NH_ + head) * 128 + 64 + i] = x2 * c + x1 * s;
        }
    } else if (part == 2) {
        for (int t = tid; t < 512; t += 256) {
            int h = t >> 6, i = t & 63;
            float x1 = rd8(qkvp, base + 4096 + h * 128 + i) * ks;
            float x2 = rd8(qkvp, base + 4096 + h * 128 + 64 + i) * ks;
            float c = cs[i], s = sn[i];
            knew[(b * NKV_ + h) * 128 + i]      = x1 * c - x2 * s;
            knew[(b * NKV_ + h) * 128 + 64 + i] = x2 * c + x1 * s;
        }
    } else {
        for (int t = tid; t < 1024; t += 256) {
            int h = t >> 7, d = t & 127;
            vnew[(b * NKV_ + h) * 128 + d] = rd8(qkvp, base + 5120 + h * 128 + d) * vs;
        }
    }
}

// ---------------------------------------------------------------------------
// Kernel 3: flash-decoding attention chunk.  grid (NCHUNK, B*NKV).
// R9 skeleton; pass 1 now 4-tokens-per-group with all 8 int4 loads issued
// up front (128 B/lane in flight, mirroring pass 2's proven depth).
__global__ __launch_bounds__(256) void attn_decode(const int* __restrict__ kc,
                                                   const int* __restrict__ vc,
                                                   const int* __restrict__ btab,
                                                   const int* __restrict__ ctx_lens,
                                                   const float* __restrict__ qf,
                                                   const float* ks_p, const float* vs_p,
                                                   float* __restrict__ po,
                                                   float* __restrict__ pm,
                                                   float* __restrict__ pl) {
    const int c  = blockIdx.x;
    const int bh = blockIdx.y;
    const int b = bh >> 3, h = bh & 7;
    const int ctx = ctx_lens[b];
    const int s0g = c * CHUNK;
    const int n = min(ctx - s0g, CHUNK);
    if (n <= 0) return;

    __shared__ float sc[4][264];        // CHUNK + pad
    __shared__ float opart[512][9];     // [g*128+d][spart]
    __shared__ int   bts[CHUNK / 16];

    const int tid = threadIdx.x;
    const int wv  = tid >> 6;
    const int l   = tid & 63;
    const int tok = l >> 4;             // group index within wave
    const int dq  = l & 15;             // 8-dim slice

    if (tid < CHUNK / 16) bts[tid] = btab[b * 128 + (s0g >> 4) + tid];

    const float kss = ks_p[0] * 0.08838834764831845f;
    const float vscale = vs_p[0];

    float qr[4][8];
#pragma unroll
    for (int g = 0; g < 4; ++g) {
        const float* qp = qf + (long)(b * NH_ + h * 4 + g) * 128 + dq * 8;
        float4 v0 = *(const float4*)(qp);
        float4 v1 = *(const float4*)(qp + 4);
        qr[g][0]=v0.x; qr[g][1]=v0.y; qr[g][2]=v0.z; qr[g][3]=v0.w;
        qr[g][4]=v1.x; qr[g][5]=v1.y; qr[g][6]=v1.z; qr[g][7]=v1.w;
    }
    __syncthreads();   // bts ready

    // ---- pass 1: scores.  64 tokens/block/sweep; group = 4 consecutive tokens,
    // 8 int4 K-loads issued up front per group (128 B/lane in flight).
    {
        const int grp = wv * 4 + tok;       // 0..15
        const int nsweep = (n + 63) >> 6;
        int base = grp * 4;
#pragma unroll 1
        for (int it = 0; it < nsweep; ++it) {
            int4 wA[4], wB[4];
#pragma unroll
            for (int t = 0; t < 4; ++t) {
                int seff = min(base + t, n - 1);
                long off = (long)(bts[seff >> 4] * 16 + (seff & 15)) * 1024 + h * 128 + dq * 8;
                wA[t] = *(const int4*)(kc + off);
                wB[t] = *(const int4*)(kc + off + 4);
            }
#pragma unroll
            for (int t = 0; t < 4; ++t) {
                float kf[8];
                kf[0]=(float)wA[t].x; kf[1]=(float)wA[t].y; kf[2]=(float)wA[t].z; kf[3]=(float)wA[t].w;
                kf[4]=(float)wB[t].x; kf[5]=(float)wB[t].y; kf[6]=(float)wB[t].z; kf[7]=(float)wB[t].w;
                float p0 = 0.f, p1 = 0.f, p2 = 0.f, p3 = 0.f;
#pragma unroll
                for (int j = 0; j < 8; ++j) {
                    p0 += qr[0][j] * kf[j];
                    p1 += qr[1][j] * kf[j];
                    p2 += qr[2][j] * kf[j];
                    p3 += qr[3][j] * kf[j];
                }
#pragma unroll
                for (int off = 1; off < 16; off <<= 1) {
                    p0 += __shfl_xor(p0, off, 16);
                    p1 += __shfl_xor(p1, off, 16);
                    p2 += __shfl_xor(p2, off, 16);
                    p3 += __shfl_xor(p3, off, 16);
                }
                int srel = base + t;
                if (srel < n && dq < 4) {
                    float psel = (dq == 0) ? p0 : (dq == 1) ? p1 : (dq == 2) ? p2 : p3;
                    sc[dq][srel] = psel * kss;
                }
            }
            base += 64;
        }
    }
    __syncthreads();

    // ---- softmax per head: wave wv owns g = wv.  Emit m, l; sc -> exp.
    {
        float m = -1e30f;
        for (int s = l; s < n; s += 64) m = fmaxf(m, sc[wv][s]);
#pragma unroll
        for (int off = 1; off < 64; off <<= 1) m = fmaxf(m, __shfl_xor(m, off, 64));
        float sum = 0.f;
        for (int s = l; s < n; s += 64) {
            float e = __expf(sc[wv][s] - m);
            sc[wv][s] = e;
            sum += e;
        }
#pragma unroll
        for (int off = 1; off < 64; off <<= 1) sum += __shfl_xor(sum, off, 64);
        if (l == 0) {
            int idx = (c * 512 + bh) * 4 + wv;
            pm[idx] = m;
            pl[idx] = sum;
        }
    }
    __syncthreads();

    // ---- pass 2: PV.  thread = (spart of 8, d4 of 32); 8 tokens batched.  (R9)
    const int d4 = tid & 31;
    const int sp = tid >> 5;
    float acc[4][4] = {};
    int s = sp;
#pragma unroll 1
    for (; s + 56 < n; s += 64) {
        int4 w[8];
#pragma unroll
        for (int j = 0; j < 8; ++j) {
            int ss = s + 8 * j;
            int blk = bts[ss >> 4];
            w[j] = *(const int4*)(vc + (long)(blk * 16 + (ss & 15)) * 1024 + h * 128 + d4 * 4);
        }
#pragma unroll
        for (int j = 0; j < 8; ++j) {
            int ss = s + 8 * j;
            float v0 = (float)w[j].x, v1 = (float)w[j].y, v2 = (float)w[j].z, v3 = (float)w[j].w;
#pragma unroll
            for (int g = 0; g < 4; ++g) {
                float p = sc[g][ss];
                acc[g][0] += p * v0; acc[g][1] += p * v1;
                acc[g][2] += p * v2; acc[g][3] += p * v3;
            }
        }
    }
#pragma unroll 1
    for (; s < n; s += 8) {
        int blk = bts[s >> 4];
        int4 w = *(const int4*)(vc + (long)(blk * 16 + (s & 15)) * 1024 + h * 128 + d4 * 4);
        float v0 = (float)w.x, v1 = (float)w.y, v2 = (float)w.z, v3 = (float)w.w;
#pragma unroll
        for (int g = 0; g < 4; ++g) {
            float p = sc[g][s];
            acc[g][0] += p * v0; acc[g][1] += p * v1;
            acc[g][2] += p * v2; acc[g][3] += p * v3;
        }
    }
#pragma unroll
    for (int g = 0; g < 4; ++g)
#pragma unroll
        for (int j = 0; j < 4; ++j)
            opart[g * 128 + d4 * 4 + j][sp] = acc[g][j];
    __syncthreads();

    for (int oi = tid; oi < 512; oi += 256) {
        float o = 0.f;
#pragma unroll
        for (int p = 0; p < 8; ++p) o += opart[oi][p];
        po[(long)((c * 512 + bh) * 4 + (oi >> 7)) * 128 + (oi & 127)] = o * vscale;
    }
}

// ---------------------------------------------------------------------------
// Kernel 4: merge chunk partials + new-token term -> attn (bf16).  (R9 verbatim)
__global__ __launch_bounds__(256) void attn_merge(const float* __restrict__ qf,
                                                  const float* __restrict__ knew,
                                                  const float* __restrict__ vnew,
                                                  const int* __restrict__ ctx_lens,
                                                  const float* __restrict__ po,
                                                  const float* __restrict__ pm,
                                                  const float* __restrict__ pl,
                                                  unsigned short* __restrict__ attn) {
    const int bh = blockIdx.x;
    const int b = bh >> 3, h = bh & 7;
    const int ctx = ctx_lens[b];
    const int nc = (ctx + CHUNK - 1) / CHUNK;
    const int tid = threadIdx.x;
    const int wv = tid >> 6, l = tid & 63;
    __shared__ float snew_s[4];

    {
        const float* kn = knew + (b * NKV_ + h) * 128;
        const float* qp = qf + (long)(b * NH_ + h * 4 + wv) * 128;
        float p = qp[l] * kn[l] + qp[l + 64] * kn[l + 64];
#pragma unroll
        for (int off = 1; off < 64; off <<= 1) p += __shfl_xor(p, off, 64);
        if (l == 0) snew_s[wv] = p * 0.08838834764831845f;
    }
    __syncthreads();

    for (int oi = tid; oi < 512; oi += 256) {
        int g = oi >> 7, d = oi & 127;
        float snew = snew_s[g];
        float M = snew;
        for (int c = 0; c < nc; ++c)
            M = fmaxf(M, pm[(c * 512 + bh) * 4 + g]);
        float wn = __expf(snew - M);
        float L = wn;
        float O = wn * vnew[(b * NKV_ + h) * 128 + d];
        for (int c = 0; c < nc; ++c) {
            float w = __expf(pm[(c * 512 + bh) * 4 + g] - M);
            L += pl[(c * 512 + bh) * 4 + g] * w;
            O += po[(long)((c * 512 + bh) * 4 + g) * 128 + d] * w;
        }
        float res = O / L;
        unsigned int u = __float_as_uint(res);
        unsigned int r = (u + 0x7fffu + ((u >> 16) & 1u)) >> 16;   // RNE to bf16
        attn[b * 4096 + (h * 4 + g) * 128 + d] = (unsigned short)r;
    }
}

// ---------------------------------------------------------------------------
// Kernel 5: o_proj GEMM, K-split x16 (qkv structure clone; R12 showed the old
// 256-block oproj at 12% occupancy / 2.3 TB/s).  grid (64, 16) = 1024 blocks.
__global__ __launch_bounds__(256) void oproj_gemm(const unsigned short* __restrict__ Abf,
                                                  const int* __restrict__ W,
                                                  float* __restrict__ Cp) {
    __shared__ unsigned short Wl[2][64 * 72];   // [n][kk] bf16, stride 72 hw
    const int tid = threadIdx.x;
    const int n0  = blockIdx.x * 64;
    const int ky  = blockIdx.y;
    const int kbeg = ky * (HIDDEN_ / OSPLIT);   // 256
    const int wv  = tid >> 6;
    const int l   = tid & 63;
    const int lr  = l & 15;
    const int lk  = l >> 4;
    const int sn  = tid & 63;
    const int sk  = (tid >> 6) * 16;

    const int* Wg = W + (long)(kbeg + sk) * HIDDEN_ + n0 + sn;

    f32x4 acc[4] = {f32x4{0,0,0,0}, f32x4{0,0,0,0}, f32x4{0,0,0,0}, f32x4{0,0,0,0}};
    int rA[16], rB[16];

#define LOADO(R, CH) { const int* wp = Wg + (long)(CH) * 64 * HIDDEN_;           \
    _Pragma("unroll") for (int j = 0; j < 16; ++j) R[j] = wp[j * HIDDEN_]; }
#define STAGEO(R, BUF) { unsigned short hb[16];                                  \
    _Pragma("unroll") for (int j = 0; j < 16; ++j)                               \
        hb[j] = (unsigned short)(__float_as_uint((float)R[j]) >> 16);            \
    *(v4i*)&Wl[BUF][sn * 72 + sk]     = *(v4i*)&hb[0];                           \
    *(v4i*)&Wl[BUF][sn * 72 + sk + 8] = *(v4i*)&hb[8]; }
#define COMPO(BUF, CH) { _Pragma("unroll") for (int kh = 0; kh < 2; ++kh) {      \
    bf8 a = *(const bf8*)(Abf + (long)(wv*16+lr)*HIDDEN_ + kbeg + (CH)*64 + kh*32 + lk*8); \
    _Pragma("unroll") for (int nt = 0; nt < 4; ++nt) {                           \
        bf8 bb = *(const bf8*)&Wl[BUF][(nt*16+lr)*72 + kh*32 + lk*8];            \
        acc[nt] = __builtin_amdgcn_mfma_f32_16x16x32_bf16(a, bb, acc[nt], 0,0,0); } } }

    LOADO(rA, 0);
#pragma unroll 1
    for (int ch = 0; ch < 4; ch += 2) {
        STAGEO(rA, 0);
        LOADO(rB, ch + 1);
        __syncthreads();
        COMPO(0, ch);
        STAGEO(rB, 1);
        if (ch < 2) LOADO(rA, ch + 2);
        __syncthreads();
        COMPO(1, ch + 1);
    }
    float* Co = Cp + (long)ky * OPROJ_PART;
#pragma unroll
    for (int nt = 0; nt < 4; ++nt)
#pragma unroll
        for (int r = 0; r < 4; ++r) {
            int m = wv * 16 + (l >> 4) * 4 + r;
            int n = n0 + nt * 16 + (l & 15);
            Co[m * HIDDEN_ + n] = acc[nt][r];
        }
#undef LOADO
#undef STAGEO
#undef COMPO
}

// Kernel 6: reduce 16 oproj partials + output scale.  grid 1024.
__global__ __launch_bounds__(256) void oproj_reduce(const float* __restrict__ Cp,
                                                    const float* os_p,
                                                    float* __restrict__ out) {
    const int i = blockIdx.x * 256 + threadIdx.x;   // 0 .. 262143
    float s = 0.f;
#pragma unroll
    for (int p = 0; p < OSPLIT; ++p) s += Cp[(long)p * OPROJ_PART + i];
    out[i] = s * os_p[0];
}

// ---------------------------------------------------------------------------
extern "C" void kernel_launch(void* const* d_in, const int* in_sizes, int n_in,
                              void* d_out, int out_size, void* d_ws, size_t ws_size,
                              hipStream_t stream) {
    const int*   positions = (const int*)d_in[0];
    const int*   hidden    = (const int*)d_in[1];
    const int*   w_qkv     = (const int*)d_in[2];
    const int*   w_o       = (const int*)d_in[3];
    const int*   kcache    = (const int*)d_in[4];
    const int*   vcache    = (const int*)d_in[5];
    const int*   btab      = (const int*)d_in[6];
    const int*   ctxl      = (const int*)d_in[7];
    const float* qs        = (const float*)d_in[8];
    const float* ks        = (const float*)d_in[9];
    const float* vs        = (const float*)d_in[10];
    const float* os        = (const float*)d_in[11];

    // Region [0, 16.78MB) is time-shared (same-stream sequential):
    //   qkvp (12.58MB, k1->k2), po (8.39MB, k3->k4), opp (16.78MB, k5->k6).
    char* ws = (char*)d_ws;
    int*            qkvp  = (int*)ws;
    float*          po    = (float*)ws;
    float*          opp   = (float*)ws;
    float*          qf    = (float*)(ws + 16777216);            //  1,048,576
    float*          knew  = (float*)(ws + 17825792);            //    262,144
    float*          vnew  = (float*)(ws + 18087936);            //    262,144
    unsigned short* attnb = (unsigned short*)(ws + 18350080);   //    524,288
    float*          pm    = (float*)(ws + 18874368);            //     65,536
    float*          pl    = (float*)(ws + 19005440);            //     65,536

    qkv_gemm<<<dim3(NQKV / 64, KSPLIT), 256, 0, stream>>>(hidden, w_qkv, qkvp);
    rope_dequant<<<dim3(B_, 4), 256, 0, stream>>>(qkvp, positions, qs, ks, vs, qf, knew, vnew);
    attn_decode<<<dim3(NCHUNK, B_ * NKV_), 256, 0, stream>>>(kcache, vcache, btab, ctxl,
                                                             qf, ks, vs, po, pm, pl);
    attn_merge<<<B_ * NKV_, 256, 0, stream>>>(qf, knew, vnew, ctxl, po, pm, pl, attnb);
    oproj_gemm<<<dim3(HIDDEN_ / 64, OSPLIT), 256, 0, stream>>>(attnb, w_o, opp);
    oproj_reduce<<<HIDDEN_ * B_ / 256, 256, 0, stream>>>(opp, os, (float*)d_out);
}